// Round 15
// baseline (47.449 us; speedup 1.0000x reference)
//
#include <hip/hip_runtime.h>

// ChamferDistance: B=4, N=M=8192, fp32 3-D points.
// R15: OCCUPANCY round. Every structure R5-R14 (global-stream, reg-pipeline,
// A-reuse, LDS-staged) pinned at 34-40 µs vs an ~8-10 µs two-pipe floor, with
// warm counters (R9) showing pipe busy-times == floors but 75% wall-time idle
// and <=2 waves/SIMD effective: the f32x16 acc/rmin sets pushed unified
// VGPR+AGPR allocation past 128 regs in every variant (rocprof VGPR_Count
// hides the AGPR half). TLP never existed. Fix: 16x16x32 MFMA shape
// (f32x4 acc, layouts VERIFIED in R4: absmax 0.0156) -> live set ~45 regs,
// __launch_bounds__(256,8) pins the <=64-reg bucket = 8 waves/SIMD (m69).
// K=16 data zero-padded to K=32 IN STORAGE (kq2,3 written as zeros) -> no
// exec-masked loads, contiguous 512 B/wave tile reads. No LDS, no barriers,
// depth-2 reg prefetch, grid 2048 = 8 blocks/CU = full 32 waves/CU.
// Math unchanged (verified since R4): d = n1+n2-2x.y, hi/lo compensated,
// two orientations, row-min in regs, int-punned atomicMin combine.

typedef short  short8 __attribute__((ext_vector_type(8)));
typedef float  f32x4  __attribute__((ext_vector_type(4)));

#define B_      4
#define NPT     8192
#define THREADS 256
#define NROWBLK 64               // 8192/128 rows per block
#define NCHUNK  4                // col chunks -> grid = 2*4*64*4 = 2048 = 8/CU
#define CCOLS   (NPT / NCHUNK)   // 2048 cols per chunk
#define NTILE   (CCOLS / 16)     // 128 16-col tiles per chunk
#define PINF_I  0x7f800000

__device__ __forceinline__ unsigned short f2bf(float x) {
    unsigned u = __float_as_uint(x);
    u += 0x7fff + ((u >> 16) & 1);
    return (unsigned short)(u >> 16);
}
__device__ __forceinline__ float bf2f(unsigned short b) {
    return __uint_as_float(((unsigned)b) << 16);
}
#define PK2(a, b) ((((unsigned)(b)) << 16) | (unsigned)(a))

// Packed layout (both A-form and B-form, zero-padded K=32):
// per 16-point group g, uint4 index = g*64 + kq*16 + slot  (kq=0..3, slot=i&15)
//   kq0 = k0..7 data, kq1 = k8..15 data, kq2/kq3 = zeros (written explicitly
//   because d_ws is poisoned 0xAA).
// A lane (row=l15, kq=lane>>4) reads 8 ushorts at g*512 + kq*128 + l15*8:
// contiguous 128 B per 16-lane quarter -> no masking, no divergence.

__global__ __launch_bounds__(THREADS)
void cd_pack(const float* __restrict__ xyz1, const float* __restrict__ xyz2,
             unsigned short* __restrict__ A1, unsigned short* __restrict__ B1,
             unsigned short* __restrict__ A2, unsigned short* __restrict__ B2,
             int* __restrict__ out) {
    int i = blockIdx.x * THREADS + threadIdx.x;
    if (i >= B_ * NPT) return;
    const unsigned short one = 0x3f80;
    const uint4 zz = make_uint4(0, 0, 0, 0);

    const size_t u4 = ((size_t)(i >> 4)) * 64 + (i & 15);   // kq0 slot

    {   // cloud 1 -> A1 + B1
        float x0 = xyz1[3*i], x1 = xyz1[3*i+1], x2 = xyz1[3*i+2];
        unsigned short h0 = f2bf(x0), h1 = f2bf(x1), h2 = f2bf(x2);
        unsigned short l0 = f2bf(x0 - bf2f(h0)), l1 = f2bf(x1 - bf2f(h1)), l2 = f2bf(x2 - bf2f(h2));
        unsigned short m0 = f2bf(-2.f * bf2f(h0)), m1 = f2bf(-2.f * bf2f(h1)), m2 = f2bf(-2.f * bf2f(h2));
        unsigned short q0 = f2bf(-2.f * bf2f(l0)), q1 = f2bf(-2.f * bf2f(l1)), q2 = f2bf(-2.f * bf2f(l2));
        float n = x0*x0 + x1*x1 + x2*x2;
        unsigned short nh = f2bf(n), nl = f2bf(n - bf2f(nh));
        ((uint4*)A1)[u4]      = make_uint4(PK2(m0, m1), PK2(m2, q0), PK2(q1, q2), PK2(m0, m1));
        ((uint4*)A1)[u4 + 16] = make_uint4(PK2(m2, nh), PK2(nl, one), PK2(one, 0), PK2(0, 0));
        ((uint4*)A1)[u4 + 32] = zz;
        ((uint4*)A1)[u4 + 48] = zz;
        ((uint4*)B1)[u4]      = make_uint4(PK2(h0, h1), PK2(h2, h0), PK2(h1, h2), PK2(l0, l1));
        ((uint4*)B1)[u4 + 16] = make_uint4(PK2(l2, one), PK2(one, nh), PK2(nl, 0), PK2(0, 0));
        ((uint4*)B1)[u4 + 32] = zz;
        ((uint4*)B1)[u4 + 48] = zz;
    }
    {   // cloud 2 -> A2 + B2
        float x0 = xyz2[3*i], x1 = xyz2[3*i+1], x2 = xyz2[3*i+2];
        unsigned short h0 = f2bf(x0), h1 = f2bf(x1), h2 = f2bf(x2);
        unsigned short l0 = f2bf(x0 - bf2f(h0)), l1 = f2bf(x1 - bf2f(h1)), l2 = f2bf(x2 - bf2f(h2));
        unsigned short m0 = f2bf(-2.f * bf2f(h0)), m1 = f2bf(-2.f * bf2f(h1)), m2 = f2bf(-2.f * bf2f(h2));
        unsigned short q0 = f2bf(-2.f * bf2f(l0)), q1 = f2bf(-2.f * bf2f(l1)), q2 = f2bf(-2.f * bf2f(l2));
        float n = x0*x0 + x1*x1 + x2*x2;
        unsigned short nh = f2bf(n), nl = f2bf(n - bf2f(nh));
        ((uint4*)A2)[u4]      = make_uint4(PK2(m0, m1), PK2(m2, q0), PK2(q1, q2), PK2(m0, m1));
        ((uint4*)A2)[u4 + 16] = make_uint4(PK2(m2, nh), PK2(nl, one), PK2(one, 0), PK2(0, 0));
        ((uint4*)A2)[u4 + 32] = zz;
        ((uint4*)A2)[u4 + 48] = zz;
        ((uint4*)B2)[u4]      = make_uint4(PK2(h0, h1), PK2(h2, h0), PK2(h1, h2), PK2(l0, l1));
        ((uint4*)B2)[u4 + 16] = make_uint4(PK2(l2, one), PK2(one, nh), PK2(nl, 0), PK2(0, 0));
        ((uint4*)B2)[u4 + 32] = zz;
        ((uint4*)B2)[u4 + 48] = zz;
    }
    out[i] = PINF_I;
    out[(size_t)B_ * NPT + i] = PINF_I;
}

// One 16-col tile against both 16-row tiles: 2 MFMA + 8 fmin, acc = 4 regs.
#define CD_TILE(bf)                                                              \
    {                                                                            \
        f32x4 z = {0.f, 0.f, 0.f, 0.f};                                          \
        f32x4 a0 = __builtin_amdgcn_mfma_f32_16x16x32_bf16(afrag0, bf, z, 0, 0, 0); \
        rmin0[0] = fminf(rmin0[0], a0[0]); rmin0[1] = fminf(rmin0[1], a0[1]);    \
        rmin0[2] = fminf(rmin0[2], a0[2]); rmin0[3] = fminf(rmin0[3], a0[3]);    \
        f32x4 a1 = __builtin_amdgcn_mfma_f32_16x16x32_bf16(afrag1, bf, z, 0, 0, 0); \
        rmin1[0] = fminf(rmin1[0], a1[0]); rmin1[1] = fminf(rmin1[1], a1[1]);    \
        rmin1[2] = fminf(rmin1[2], a1[2]); rmin1[3] = fminf(rmin1[3], a1[3]);    \
    }

#define CD_LOAD(bf, tn)                                                          \
    {                                                                            \
        int tt = (tn) < NTILE ? (tn) : NTILE - 1;                                \
        bf = *(const short8*)(gB + (size_t)tt * 512);                            \
    }

__global__ __launch_bounds__(THREADS, 8)    // pin <=64-reg bucket: 8 waves/SIMD
void cd_mfma16(const unsigned short* __restrict__ A1, const unsigned short* __restrict__ B1,
               const unsigned short* __restrict__ A2, const unsigned short* __restrict__ B2,
               int* __restrict__ out) {
    int bid = blockIdx.x;
    const int c    = bid & (NCHUNK - 1);   bid >>= 2;  // 4 chunks
    const int rb   = bid & (NROWBLK - 1);  bid >>= 6;  // 64 row-blocks
    const int b    = bid & (B_ - 1);       bid >>= 2;
    const int pass = bid;                               // 0: dist1, 1: dist2

    const unsigned short* __restrict__ Ap = pass ? A2 : A1;
    const unsigned short* __restrict__ Bp = pass ? B1 : B2;
    int* __restrict__ o = out + (size_t)pass * B_ * NPT;

    const int lane = threadIdx.x & 63;
    const int w    = threadIdx.x >> 6;
    const int l15  = lane & 15;
    const int kq   = lane >> 4;            // k-quarter: k = kq*8 + i (kq2,3 read stored zeros)

    const size_t bbase   = (size_t)b * NPT;     // points
    const int    rowBase = rb * 128 + w * 32;   // 32 rows per wave (2 x 16)

    // A fragments: zero-padded split-K4 layout, no masking
    const unsigned short* __restrict__ gA =
        Ap + bbase * 32 + (size_t)(rowBase >> 4) * 512 + kq * 128 + l15 * 8;
    short8 afrag0 = *(const short8*)(gA);
    short8 afrag1 = *(const short8*)(gA + 512);

    f32x4 rmin0 = {__int_as_float(PINF_I), __int_as_float(PINF_I),
                   __int_as_float(PINF_I), __int_as_float(PINF_I)};
    f32x4 rmin1 = rmin0;

    // B chunk base: tile t = 16-pt group; lane reads 8 ushorts at
    // t*512 + kq*128 + l15*8 -> contiguous 128 B per 16-lane quarter.
    const unsigned short* __restrict__ gB =
        Bp + bbase * 32 + (size_t)c * CCOLS * 32 + kq * 128 + l15 * 8;

    short8 bfA, bfB;
    CD_LOAD(bfA, 0)
    CD_LOAD(bfB, 1)

    for (int t = 0; t < NTILE; t += 2) {
        CD_TILE(bfA)
        CD_LOAD(bfA, t + 2)
        CD_TILE(bfB)
        CD_LOAD(bfB, t + 3)
    }

    // Epilogue: reduce each rmin reg across the 16 col-lanes; lanes with
    // l15==0 (one per kq) write rows rowBase + rt*16 + kq*4 + r.
    #pragma unroll
    for (int rt = 0; rt < 2; ++rt) {
        #pragma unroll
        for (int r = 0; r < 4; ++r) {
            float v = rt ? rmin1[r] : rmin0[r];
            v = fminf(v, __shfl_xor(v, 1, 64));
            v = fminf(v, __shfl_xor(v, 2, 64));
            v = fminf(v, __shfl_xor(v, 4, 64));
            v = fminf(v, __shfl_xor(v, 8, 64));
            if (l15 == 0) {
                int row = rowBase + rt * 16 + kq * 4 + r;
                atomicMin(&o[bbase + row], __float_as_int(fmaxf(v, 0.f)));
            }
        }
    }
}

extern "C" void kernel_launch(void* const* d_in, const int* in_sizes, int n_in,
                              void* d_out, int out_size, void* d_ws, size_t ws_size,
                              hipStream_t stream) {
    const float* xyz1 = (const float*)d_in[0];
    const float* xyz2 = (const float*)d_in[1];

    const size_t PSZ = (size_t)B_ * NPT * 32;       // ushorts per packed array (2 MB)
    unsigned short* A1 = (unsigned short*)d_ws;     // 4 x 2 MB in d_ws
    unsigned short* B1 = A1 + PSZ;
    unsigned short* A2 = B1 + PSZ;
    unsigned short* B2 = A2 + PSZ;

    cd_pack<<<(B_ * NPT + THREADS - 1) / THREADS, THREADS, 0, stream>>>(
        xyz1, xyz2, A1, B1, A2, B2, (int*)d_out);

    cd_mfma16<<<2 * B_ * NROWBLK * NCHUNK, THREADS, 0, stream>>>(
        A1, B1, A2, B2, (int*)d_out);
}

// Round 16
// 42.928 us; speedup vs baseline: 1.1053x; 1.1053x over previous
//
#include <hip/hip_runtime.h>

// ChamferDistance: B=4, N=M=8192, fp32 3-D points.
// R16: ONE-orientation dual-min. R5-R15 falsified load-latency, VALU-count,
// per-CU-bytes, barrier, and occupancy theories — every two-orientation
// variant times at 37.1-37.8 µs (timed dur_us; profiled kernel durs proved
// inflated by R3's 2x46.5µs-in-52.3µs contradiction). Last unhalved factor:
// d is computed TWICE (once per orientation). This round computes d once:
//   dist1 = row-min in regs (as before);
//   dist2 = col-min = in-lane min3 TREE over the lane's 32 acc values
//           (col = lane&31 for both row-tiles), one ds_write per tile into
//           colsh[w*2+kg][t*32+col] (write-once, no atomics, 2-way banks =
//           free), block-reduced 8->1 after ONE barrier, 1024 atomics/block.
// Halves: MFMA count, B loads, L2 traffic, tiles/wave (64->32), pack work.
// Register shape = R5's proven core (VGPR 36, no spill): acc0/acc1 only
// (32 regs) live, no min3 pairing of B tiles.
// Math verified since R4 (absmax 0.0156): d = n1+n2-2x.y, hi/lo bf16 K=16;
// C layout 32x32: col=lane&31, row=(r&3)+8*(r>>2)+4*(lane>>5).

typedef short  short8 __attribute__((ext_vector_type(8)));
typedef float  f32x16 __attribute__((ext_vector_type(16)));

#define B_      4
#define NPT     8192
#define THREADS 256
#define NROWBLK 32               // 256 rows per block
#define NCHUNK  8                // 1024 cols per chunk -> grid 4*32*8 = 1024
#define CCOLS   (NPT / NCHUNK)   // 1024
#define NTILE   (CCOLS / 32)     // 32 tiles
#define PINF_I  0x7f800000

__device__ __forceinline__ unsigned short f2bf(float x) {
    unsigned u = __float_as_uint(x);
    u += 0x7fff + ((u >> 16) & 1);
    return (unsigned short)(u >> 16);
}
__device__ __forceinline__ float bf2f(unsigned short b) {
    return __uint_as_float(((unsigned)b) << 16);
}
#define PK2(a, b) ((((unsigned)(b)) << 16) | (unsigned)(a))

__global__ __launch_bounds__(THREADS)
void cd_pack(const float* __restrict__ xyz1, const float* __restrict__ xyz2,
             unsigned short* __restrict__ A1, unsigned short* __restrict__ B2,
             int* __restrict__ out) {
    int i = blockIdx.x * THREADS + threadIdx.x;
    if (i >= B_ * NPT) return;
    const unsigned short one = 0x3f80;

    {   // cloud 1 -> A-form, linear (rows of d)
        float x0 = xyz1[3*i], x1 = xyz1[3*i+1], x2 = xyz1[3*i+2];
        unsigned short h0 = f2bf(x0), h1 = f2bf(x1), h2 = f2bf(x2);
        unsigned short l0 = f2bf(x0 - bf2f(h0)), l1 = f2bf(x1 - bf2f(h1)), l2 = f2bf(x2 - bf2f(h2));
        unsigned short m0 = f2bf(-2.f * bf2f(h0)), m1 = f2bf(-2.f * bf2f(h1)), m2 = f2bf(-2.f * bf2f(h2));
        unsigned short q0 = f2bf(-2.f * bf2f(l0)), q1 = f2bf(-2.f * bf2f(l1)), q2 = f2bf(-2.f * bf2f(l2));
        float n = x0*x0 + x1*x1 + x2*x2;
        unsigned short nh = f2bf(n), nl = f2bf(n - bf2f(nh));
        ((uint4*)A1)[(size_t)i * 2]     = make_uint4(PK2(m0, m1), PK2(m2, q0), PK2(q1, q2), PK2(m0, m1));
        ((uint4*)A1)[(size_t)i * 2 + 1] = make_uint4(PK2(m2, nh), PK2(nl, one), PK2(one, 0), PK2(0, 0));
    }
    {   // cloud 2 -> B-form, split-K per 32-pt group (cols of d)
        const size_t bidx = ((size_t)(i >> 5)) * 64 + (i & 31);
        float y0 = xyz2[3*i], y1 = xyz2[3*i+1], y2 = xyz2[3*i+2];
        unsigned short h0 = f2bf(y0), h1 = f2bf(y1), h2 = f2bf(y2);
        unsigned short l0 = f2bf(y0 - bf2f(h0)), l1 = f2bf(y1 - bf2f(h1)), l2 = f2bf(y2 - bf2f(h2));
        float n = y0*y0 + y1*y1 + y2*y2;
        unsigned short nh = f2bf(n), nl = f2bf(n - bf2f(nh));
        ((uint4*)B2)[bidx]      = make_uint4(PK2(h0, h1), PK2(h2, h0), PK2(h1, h2), PK2(l0, l1));
        ((uint4*)B2)[bidx + 32] = make_uint4(PK2(l2, one), PK2(one, nh), PK2(nl, 0), PK2(0, 0));
    }
    out[i] = PINF_I;                        // dist1 init
    out[(size_t)B_ * NPT + i] = PINF_I;     // dist2 init
}

// Reload one bf register with tile index tn (clamped; harmless re-read).
#define CD_LOAD(bf, tn)                                                          \
    {                                                                            \
        int tt = (tn) < NTILE ? (tn) : NTILE - 1;                                \
        bf = *(const short8*)(gB + (size_t)tt * 512);                            \
    }

// One tile: 2 MFMA, 32 row-min fmin, 16-op col-min tree, 1 ds_write.
#define CD_TILE(bf, tcol)                                                        \
    {                                                                            \
        f32x16 z = {0.f};                                                        \
        f32x16 acc0 = __builtin_amdgcn_mfma_f32_32x32x16_bf16(afrag0, bf, z, 0, 0, 0); \
        f32x16 acc1 = __builtin_amdgcn_mfma_f32_32x32x16_bf16(afrag1, bf, z, 0, 0, 0); \
        _Pragma("unroll")                                                        \
        for (int r = 0; r < 16; ++r) rmin0[r] = fminf(rmin0[r], acc0[r]);        \
        _Pragma("unroll")                                                        \
        for (int r = 0; r < 16; ++r) rmin1[r] = fminf(rmin1[r], acc1[r]);        \
        float t0 = fminf(fminf(acc0[0],  acc0[1]),  fminf(acc0[2],  acc0[3]));   \
        float t1 = fminf(fminf(acc0[4],  acc0[5]),  fminf(acc0[6],  acc0[7]));   \
        float t2 = fminf(fminf(acc0[8],  acc0[9]),  fminf(acc0[10], acc0[11]));  \
        float t3 = fminf(fminf(acc0[12], acc0[13]), fminf(acc0[14], acc0[15]));  \
        float u0 = fminf(fminf(acc1[0],  acc1[1]),  fminf(acc1[2],  acc1[3]));   \
        float u1 = fminf(fminf(acc1[4],  acc1[5]),  fminf(acc1[6],  acc1[7]));   \
        float u2 = fminf(fminf(acc1[8],  acc1[9]),  fminf(acc1[10], acc1[11]));  \
        float u3 = fminf(fminf(acc1[12], acc1[13]), fminf(acc1[14], acc1[15]));  \
        float cm = fminf(fminf(fminf(t0, t1), fminf(t2, t3)),                    \
                         fminf(fminf(u0, u1), fminf(u2, u3)));                   \
        colsh[((w << 1) + kg) * 1024 + (tcol) * 32 + l31] = cm;                  \
    }

__global__ __launch_bounds__(THREADS, 4)
void cd_dual(const unsigned short* __restrict__ A1, const unsigned short* __restrict__ B2,
             int* __restrict__ out) {
    __shared__ float colsh[8 * 1024];       // 32 KB: [wave*2+kg][1024 cols]

    int bid = blockIdx.x;
    const int c    = bid & (NCHUNK - 1);   bid >>= 3;  // 8 chunks
    const int rb   = bid & (NROWBLK - 1);  bid >>= 5;  // 32 row-blocks
    const int b    = bid;                               // batch

    int* __restrict__ o1 = out;                          // dist1 (B,N)
    int* __restrict__ o2 = out + (size_t)B_ * NPT;       // dist2 (B,M)

    const int tid  = threadIdx.x;
    const int lane = tid & 63;
    const int w    = tid >> 6;
    const int l31  = lane & 31;
    const int kg   = lane >> 5;            // k-half: k = kg*8 + idx

    const size_t bbase   = (size_t)b * NPT;
    const int    rowBase = rb * 256 + w * 64;

    // A fragments (rows of d), resident for the whole sweep
    short8 afrag0 = *(const short8*)(A1 + (bbase + rowBase +  0 + l31) * 16 + kg * 8);
    short8 afrag1 = *(const short8*)(A1 + (bbase + rowBase + 32 + l31) * 16 + kg * 8);

    f32x16 rmin0, rmin1;
    #pragma unroll
    for (int r = 0; r < 16; ++r) {
        rmin0[r] = __int_as_float(PINF_I);
        rmin1[r] = __int_as_float(PINF_I);
    }

    // B chunk base, split-K: lane reads contiguous 16 B at t*512+kg*256+l31*8
    const unsigned short* __restrict__ gB =
        B2 + (bbase + (size_t)c * CCOLS) * 16 + kg * 256 + l31 * 8;

    short8 bfA, bfB;
    CD_LOAD(bfA, 0)
    CD_LOAD(bfB, 1)

    #pragma unroll 2
    for (int t = 0; t < NTILE; t += 2) {
        CD_TILE(bfA, t)
        CD_LOAD(bfA, t + 2)
        CD_TILE(bfB, t + 1)
        CD_LOAD(bfB, t + 3)
    }

    // dist1 epilogue: butterfly row-mins across 32 col-slots, 1 atomic/row
    #pragma unroll
    for (int rt = 0; rt < 2; ++rt) {
        #pragma unroll
        for (int r = 0; r < 16; ++r) {
            float v = rt ? rmin1[r] : rmin0[r];
            v = fminf(v, __shfl_xor(v, 1, 64));
            v = fminf(v, __shfl_xor(v, 2, 64));
            v = fminf(v, __shfl_xor(v, 4, 64));
            v = fminf(v, __shfl_xor(v, 8, 64));
            v = fminf(v, __shfl_xor(v, 16, 64));
            if (l31 == 0) {
                int row = rowBase + rt * 32 + (r & 3) + 8 * (r >> 2) + 4 * kg;
                atomicMin(&o1[bbase + row], __float_as_int(fmaxf(v, 0.f)));
            }
        }
    }

    // dist2 epilogue: reduce 8 partials per col, 1 atomic per col (1024/block)
    __syncthreads();
    {
        const float4* c4 = (const float4*)colsh;   // [8][256] float4 view
        float4 v0 = c4[tid];
        float4 v1 = c4[256 + tid];
        float4 v2 = c4[512 + tid];
        float4 v3 = c4[768 + tid];
        float4 v4 = c4[1024 + tid];
        float4 v5 = c4[1280 + tid];
        float4 v6 = c4[1536 + tid];
        float4 v7 = c4[1792 + tid];
        float m0 = fminf(fminf(fminf(v0.x, v1.x), fminf(v2.x, v3.x)),
                         fminf(fminf(v4.x, v5.x), fminf(v6.x, v7.x)));
        float m1 = fminf(fminf(fminf(v0.y, v1.y), fminf(v2.y, v3.y)),
                         fminf(fminf(v4.y, v5.y), fminf(v6.y, v7.y)));
        float m2 = fminf(fminf(fminf(v0.z, v1.z), fminf(v2.z, v3.z)),
                         fminf(fminf(v4.z, v5.z), fminf(v6.z, v7.z)));
        float m3 = fminf(fminf(fminf(v0.w, v1.w), fminf(v2.w, v3.w)),
                         fminf(fminf(v4.w, v5.w), fminf(v6.w, v7.w)));
        const size_t colBase = bbase + (size_t)c * CCOLS + tid * 4;
        atomicMin(&o2[colBase + 0], __float_as_int(fmaxf(m0, 0.f)));
        atomicMin(&o2[colBase + 1], __float_as_int(fmaxf(m1, 0.f)));
        atomicMin(&o2[colBase + 2], __float_as_int(fmaxf(m2, 0.f)));
        atomicMin(&o2[colBase + 3], __float_as_int(fmaxf(m3, 0.f)));
    }
}

extern "C" void kernel_launch(void* const* d_in, const int* in_sizes, int n_in,
                              void* d_out, int out_size, void* d_ws, size_t ws_size,
                              hipStream_t stream) {
    const float* xyz1 = (const float*)d_in[0];
    const float* xyz2 = (const float*)d_in[1];

    const size_t PSZ = (size_t)B_ * NPT * 16;       // ushorts per packed array
    unsigned short* A1 = (unsigned short*)d_ws;     // 1 MB
    unsigned short* B2 = A1 + PSZ;                  // 1 MB

    cd_pack<<<(B_ * NPT + THREADS - 1) / THREADS, THREADS, 0, stream>>>(
        xyz1, xyz2, A1, B2, (int*)d_out);

    cd_dual<<<B_ * NROWBLK * NCHUNK, THREADS, 0, stream>>>(A1, B2, (int*)d_out);
}

// Round 17
// 41.435 us; speedup vs baseline: 1.1451x; 1.0360x over previous
//
#include <hip/hip_runtime.h>

// ChamferDistance: B=4, N=M=8192, fp32 3-D points.
// R17: ACC-PIPELINED min (consume-1-behind). R5-R16 falsified every
// throughput theory (loads, VALU count, bytes, barriers, occupancy, total
// work); three different binaries timed 37.75+-0.01 µs. The one structure
// never varied: fmin always consumed the JUST-issued MFMA's acc -> per-tile
// stall = MFMA result latency (R16 counters: ~750 SIMD-cyc/tile vs ~110
// issue). This round: per phase, issue MFMA for tile t+1, reload a B slot,
// THEN fmin tile t's acc (issued a full phase earlier; x4 resident waves
// ~320 cyc coverage). Static names accA/accB (rule #20), 4 B slots.
// One row-tile per wave -> ~78 regs, safe in the <=128 bucket at (256,4).
// Two orientations (each output = pure row-min), grid 4096 = 16 blocks/CU.
// Math verified since R4 (absmax 0.0156): d = n1+n2-2x.y, hi/lo bf16 K=16;
// C layout 32x32: col=lane&31, row=(r&3)+8*(r>>2)+4*(lane>>5).

typedef short  short8 __attribute__((ext_vector_type(8)));
typedef float  f32x16 __attribute__((ext_vector_type(16)));

#define B_      4
#define NPT     8192
#define THREADS 256
#define NROWBLK 64               // 128 rows per block (32 per wave)
#define NCHUNK  8                // 1024 cols per chunk
#define CCOLS   (NPT / NCHUNK)   // 1024
#define NTILE   (CCOLS / 32)     // 32 tiles per wave
#define PINF_I  0x7f800000

__device__ __forceinline__ unsigned short f2bf(float x) {
    unsigned u = __float_as_uint(x);
    u += 0x7fff + ((u >> 16) & 1);
    return (unsigned short)(u >> 16);
}
__device__ __forceinline__ float bf2f(unsigned short b) {
    return __uint_as_float(((unsigned)b) << 16);
}
#define PK2(a, b) ((((unsigned)(b)) << 16) | (unsigned)(a))

__global__ __launch_bounds__(THREADS)
void cd_pack(const float* __restrict__ xyz1, const float* __restrict__ xyz2,
             unsigned short* __restrict__ A1, unsigned short* __restrict__ B1,
             unsigned short* __restrict__ A2, unsigned short* __restrict__ B2,
             int* __restrict__ out) {
    int i = blockIdx.x * THREADS + threadIdx.x;
    if (i >= B_ * NPT) return;
    const unsigned short one = 0x3f80;

    // B-form split-K placement: group g = i>>5, slot = i&31.
    const size_t bidx = ((size_t)(i >> 5)) * 64 + (i & 31);

    {   // cloud 1 -> A1 (linear) + B1 (split-K)
        float x0 = xyz1[3*i], x1 = xyz1[3*i+1], x2 = xyz1[3*i+2];
        unsigned short h0 = f2bf(x0), h1 = f2bf(x1), h2 = f2bf(x2);
        unsigned short l0 = f2bf(x0 - bf2f(h0)), l1 = f2bf(x1 - bf2f(h1)), l2 = f2bf(x2 - bf2f(h2));
        unsigned short m0 = f2bf(-2.f * bf2f(h0)), m1 = f2bf(-2.f * bf2f(h1)), m2 = f2bf(-2.f * bf2f(h2));
        unsigned short q0 = f2bf(-2.f * bf2f(l0)), q1 = f2bf(-2.f * bf2f(l1)), q2 = f2bf(-2.f * bf2f(l2));
        float n = x0*x0 + x1*x1 + x2*x2;
        unsigned short nh = f2bf(n), nl = f2bf(n - bf2f(nh));
        ((uint4*)A1)[(size_t)i * 2]     = make_uint4(PK2(m0, m1), PK2(m2, q0), PK2(q1, q2), PK2(m0, m1));
        ((uint4*)A1)[(size_t)i * 2 + 1] = make_uint4(PK2(m2, nh), PK2(nl, one), PK2(one, 0), PK2(0, 0));
        ((uint4*)B1)[bidx]      = make_uint4(PK2(h0, h1), PK2(h2, h0), PK2(h1, h2), PK2(l0, l1));
        ((uint4*)B1)[bidx + 32] = make_uint4(PK2(l2, one), PK2(one, nh), PK2(nl, 0), PK2(0, 0));
    }
    {   // cloud 2 -> A2 (linear) + B2 (split-K)
        float x0 = xyz2[3*i], x1 = xyz2[3*i+1], x2 = xyz2[3*i+2];
        unsigned short h0 = f2bf(x0), h1 = f2bf(x1), h2 = f2bf(x2);
        unsigned short l0 = f2bf(x0 - bf2f(h0)), l1 = f2bf(x1 - bf2f(h1)), l2 = f2bf(x2 - bf2f(h2));
        unsigned short m0 = f2bf(-2.f * bf2f(h0)), m1 = f2bf(-2.f * bf2f(h1)), m2 = f2bf(-2.f * bf2f(h2));
        unsigned short q0 = f2bf(-2.f * bf2f(l0)), q1 = f2bf(-2.f * bf2f(l1)), q2 = f2bf(-2.f * bf2f(l2));
        float n = x0*x0 + x1*x1 + x2*x2;
        unsigned short nh = f2bf(n), nl = f2bf(n - bf2f(nh));
        ((uint4*)A2)[(size_t)i * 2]     = make_uint4(PK2(m0, m1), PK2(m2, q0), PK2(q1, q2), PK2(m0, m1));
        ((uint4*)A2)[(size_t)i * 2 + 1] = make_uint4(PK2(m2, nh), PK2(nl, one), PK2(one, 0), PK2(0, 0));
        ((uint4*)B2)[bidx]      = make_uint4(PK2(h0, h1), PK2(h2, h0), PK2(h1, h2), PK2(l0, l1));
        ((uint4*)B2)[bidx + 32] = make_uint4(PK2(l2, one), PK2(one, nh), PK2(nl, 0), PK2(0, 0));
    }
    out[i] = PINF_I;
    out[(size_t)B_ * NPT + i] = PINF_I;
}

#define CD_LOAD(bf, tn)  bf = *(const short8*)(gB + (size_t)(tn) * 512);
#define CD_FMIN(acc)                                                             \
    { _Pragma("unroll") for (int r = 0; r < 16; ++r) rmin[r] = fminf(rmin[r], acc[r]); }

__global__ __launch_bounds__(THREADS, 4)    // ~78 regs, <=128 bucket, 4 waves/SIMD
void cd_mfma32(const unsigned short* __restrict__ A1, const unsigned short* __restrict__ B1,
               const unsigned short* __restrict__ A2, const unsigned short* __restrict__ B2,
               int* __restrict__ out) {
    int bid = blockIdx.x;
    const int c    = bid & (NCHUNK - 1);   bid >>= 3;  // 8 chunks
    const int rb   = bid & (NROWBLK - 1);  bid >>= 6;  // 64 row-blocks
    const int b    = bid & (B_ - 1);       bid >>= 2;
    const int pass = bid;                               // 0: dist1, 1: dist2

    const unsigned short* __restrict__ Ap = pass ? A2 : A1;
    const unsigned short* __restrict__ Bp = pass ? B1 : B2;
    int* __restrict__ o = out + (size_t)pass * B_ * NPT;

    const int lane = threadIdx.x & 63;
    const int w    = threadIdx.x >> 6;
    const int l31  = lane & 31;
    const int kg   = lane >> 5;            // k-half: k = kg*8 + idx

    const size_t bbase   = (size_t)b * NPT;
    const int    rowBase = rb * 128 + w * 32;    // ONE 32-row tile per wave

    short8 afrag = *(const short8*)(Ap + (bbase + rowBase + l31) * 16 + kg * 8);

    f32x16 rmin;
    #pragma unroll
    for (int r = 0; r < 16; ++r) rmin[r] = __int_as_float(PINF_I);

    const unsigned short* __restrict__ gB =
        Bp + (bbase + (size_t)c * CCOLS) * 16 + kg * 256 + l31 * 8;

    const f32x16 z = {0.f};

    // 4 B slots, 2 acc slots; min runs one tile behind the MFMA.
    short8 bf0, bf1, bf2, bf3;
    CD_LOAD(bf0, 0) CD_LOAD(bf1, 1) CD_LOAD(bf2, 2) CD_LOAD(bf3, 3)
    f32x16 accA = __builtin_amdgcn_mfma_f32_32x32x16_bf16(afrag, bf0, z, 0, 0, 0);
    f32x16 accB;

    // Invariant at loop top: accA = tile t issued; bf1,bf2,bf3 = t+1,t+2,t+3.
    for (int t = 0; t < NTILE - 4; t += 4) {
        accB = __builtin_amdgcn_mfma_f32_32x32x16_bf16(afrag, bf1, z, 0, 0, 0);
        CD_LOAD(bf0, t + 4)
        CD_FMIN(accA)                                        // consume t
        accA = __builtin_amdgcn_mfma_f32_32x32x16_bf16(afrag, bf2, z, 0, 0, 0);
        CD_LOAD(bf1, t + 5)
        CD_FMIN(accB)                                        // consume t+1
        accB = __builtin_amdgcn_mfma_f32_32x32x16_bf16(afrag, bf3, z, 0, 0, 0);
        CD_LOAD(bf2, t + 6)
        CD_FMIN(accA)                                        // consume t+2
        accA = __builtin_amdgcn_mfma_f32_32x32x16_bf16(afrag, bf0, z, 0, 0, 0);
        CD_LOAD(bf3, t + 7)
        CD_FMIN(accB)                                        // consume t+3
    }
    // Exit t = NTILE-4 = 28: accA = tile 28 issued; bf1=29, bf2=30, bf3=31.
    accB = __builtin_amdgcn_mfma_f32_32x32x16_bf16(afrag, bf1, z, 0, 0, 0);
    CD_FMIN(accA)                                            // 28
    accA = __builtin_amdgcn_mfma_f32_32x32x16_bf16(afrag, bf2, z, 0, 0, 0);
    CD_FMIN(accB)                                            // 29
    accB = __builtin_amdgcn_mfma_f32_32x32x16_bf16(afrag, bf3, z, 0, 0, 0);
    CD_FMIN(accA)                                            // 30
    CD_FMIN(accB)                                            // 31

    // Epilogue: butterfly row-mins across 32 col-slots, one atomic per row
    #pragma unroll
    for (int r = 0; r < 16; ++r) {
        float v = rmin[r];
        v = fminf(v, __shfl_xor(v, 1, 64));
        v = fminf(v, __shfl_xor(v, 2, 64));
        v = fminf(v, __shfl_xor(v, 4, 64));
        v = fminf(v, __shfl_xor(v, 8, 64));
        v = fminf(v, __shfl_xor(v, 16, 64));
        if (l31 == 0) {
            int row = rowBase + (r & 3) + 8 * (r >> 2) + 4 * kg;
            atomicMin(&o[bbase + row], __float_as_int(fmaxf(v, 0.f)));
        }
    }
}

extern "C" void kernel_launch(void* const* d_in, const int* in_sizes, int n_in,
                              void* d_out, int out_size, void* d_ws, size_t ws_size,
                              hipStream_t stream) {
    const float* xyz1 = (const float*)d_in[0];
    const float* xyz2 = (const float*)d_in[1];

    const size_t PSZ = (size_t)B_ * NPT * 16;       // ushorts per packed array
    unsigned short* A1 = (unsigned short*)d_ws;     // 4 x 1 MB in d_ws
    unsigned short* B1 = A1 + PSZ;
    unsigned short* A2 = B1 + PSZ;
    unsigned short* B2 = A2 + PSZ;

    cd_pack<<<(B_ * NPT + THREADS - 1) / THREADS, THREADS, 0, stream>>>(
        xyz1, xyz2, A1, B1, A2, B2, (int*)d_out);

    cd_mfma32<<<2 * B_ * NROWBLK * NCHUNK, THREADS, 0, stream>>>(
        A1, B1, A2, B2, (int*)d_out);
}

// Round 18
// 37.926 us; speedup vs baseline: 1.2511x; 1.0925x over previous
//
#include <hip/hip_runtime.h>

// ChamferDistance: B=4, N=M=8192, fp32 3-D points.
// R18: R12 EXACTLY, with __launch_bounds__(256,4) -> (256,2). Single-variable
// test of the AGPR-move-tax theory: at the 128-unified budget the allocator
// splits arch-VGPR/AGPR and places MFMA accumulators in AGPRs; unlike GEMM
// (in-place accumulate, no VALU reads), our fmin/min3 READS the acc every
// tile -> hidden v_accvgpr_read per operand (R16 counters: VALUBusy 15.3 µs
// vs ~5.9 µs source VALU = 2.6x inflation), plus pressure-driven load
// sinking (why prefetch depth 1/4/8 never mattered). At 256 regs/wave the
// ~116-reg live set fits entirely in arch VGPRs (m97: 164 arch is possible)
// -> no tax, prefetches stay hoisted. 2 waves/SIMD.
// Math unchanged (verified since R4, absmax 0.0156).

typedef short  short8 __attribute__((ext_vector_type(8)));
typedef float  f32x16 __attribute__((ext_vector_type(16)));

#define B_      4
#define NPT     8192
#define THREADS 256
#define ROWBLK  32               // 256-row blocks per (pass, batch)
#define NCHUNK  4                // col chunks -> grid = 2*4*32*4 = 1024
#define CCOLS   (NPT / NCHUNK)   // 2048 cols per chunk
#define NTILE   (CCOLS / 32)     // 64 32-col tiles per chunk
#define PINF_I  0x7f800000

__device__ __forceinline__ unsigned short f2bf(float x) {
    unsigned u = __float_as_uint(x);
    u += 0x7fff + ((u >> 16) & 1);
    return (unsigned short)(u >> 16);
}
__device__ __forceinline__ float bf2f(unsigned short b) {
    return __uint_as_float(((unsigned)b) << 16);
}
#define PK2(a, b) ((((unsigned)(b)) << 16) | (unsigned)(a))

__global__ __launch_bounds__(THREADS)
void cd_pack(const float* __restrict__ xyz1, const float* __restrict__ xyz2,
             unsigned short* __restrict__ A1, unsigned short* __restrict__ B1,
             unsigned short* __restrict__ A2, unsigned short* __restrict__ B2,
             int* __restrict__ out) {
    int i = blockIdx.x * THREADS + threadIdx.x;
    if (i >= B_ * NPT) return;
    const unsigned short one = 0x3f80;

    // B-form split-K placement: group g = i>>5, slot = i&31.
    //   uint4 idx for k0..7  : g*64 + slot ; k8..15 : g*64 + 32 + slot
    const size_t bidx = ((size_t)(i >> 5)) * 64 + (i & 31);

    {   // cloud 1 -> A1 (linear) + B1 (split-K)
        float x0 = xyz1[3*i], x1 = xyz1[3*i+1], x2 = xyz1[3*i+2];
        unsigned short h0 = f2bf(x0), h1 = f2bf(x1), h2 = f2bf(x2);
        unsigned short l0 = f2bf(x0 - bf2f(h0)), l1 = f2bf(x1 - bf2f(h1)), l2 = f2bf(x2 - bf2f(h2));
        unsigned short m0 = f2bf(-2.f * bf2f(h0)), m1 = f2bf(-2.f * bf2f(h1)), m2 = f2bf(-2.f * bf2f(h2));
        unsigned short q0 = f2bf(-2.f * bf2f(l0)), q1 = f2bf(-2.f * bf2f(l1)), q2 = f2bf(-2.f * bf2f(l2));
        float n = x0*x0 + x1*x1 + x2*x2;
        unsigned short nh = f2bf(n), nl = f2bf(n - bf2f(nh));
        ((uint4*)A1)[(size_t)i * 2]     = make_uint4(PK2(m0, m1), PK2(m2, q0), PK2(q1, q2), PK2(m0, m1));
        ((uint4*)A1)[(size_t)i * 2 + 1] = make_uint4(PK2(m2, nh), PK2(nl, one), PK2(one, 0), PK2(0, 0));
        ((uint4*)B1)[bidx]      = make_uint4(PK2(h0, h1), PK2(h2, h0), PK2(h1, h2), PK2(l0, l1));
        ((uint4*)B1)[bidx + 32] = make_uint4(PK2(l2, one), PK2(one, nh), PK2(nl, 0), PK2(0, 0));
    }
    {   // cloud 2 -> A2 (linear) + B2 (split-K)
        float x0 = xyz2[3*i], x1 = xyz2[3*i+1], x2 = xyz2[3*i+2];
        unsigned short h0 = f2bf(x0), h1 = f2bf(x1), h2 = f2bf(x2);
        unsigned short l0 = f2bf(x0 - bf2f(h0)), l1 = f2bf(x1 - bf2f(h1)), l2 = f2bf(x2 - bf2f(h2));
        unsigned short m0 = f2bf(-2.f * bf2f(h0)), m1 = f2bf(-2.f * bf2f(h1)), m2 = f2bf(-2.f * bf2f(h2));
        unsigned short q0 = f2bf(-2.f * bf2f(l0)), q1 = f2bf(-2.f * bf2f(l1)), q2 = f2bf(-2.f * bf2f(l2));
        float n = x0*x0 + x1*x1 + x2*x2;
        unsigned short nh = f2bf(n), nl = f2bf(n - bf2f(nh));
        ((uint4*)A2)[(size_t)i * 2]     = make_uint4(PK2(m0, m1), PK2(m2, q0), PK2(q1, q2), PK2(m0, m1));
        ((uint4*)A2)[(size_t)i * 2 + 1] = make_uint4(PK2(m2, nh), PK2(nl, one), PK2(one, 0), PK2(0, 0));
        ((uint4*)B2)[bidx]      = make_uint4(PK2(h0, h1), PK2(h2, h0), PK2(h1, h2), PK2(l0, l1));
        ((uint4*)B2)[bidx + 32] = make_uint4(PK2(l2, one), PK2(one, nh), PK2(nl, 0), PK2(0, 0));
    }
    out[i] = PINF_I;
    out[(size_t)B_ * NPT + i] = PINF_I;
}

// Pair-compute on two B tiles: row-tile 0's acc pair is produced and fully
// consumed (min3) before row-tile 1's — keeps one 32-reg acc pair live.
#define CD_PAIR(bx, by)                                                          \
    {                                                                            \
        f32x16 z = {0.f};                                                        \
        f32x16 accX = __builtin_amdgcn_mfma_f32_32x32x16_bf16(afrag0, bx, z, 0, 0, 0); \
        f32x16 accY = __builtin_amdgcn_mfma_f32_32x32x16_bf16(afrag0, by, z, 0, 0, 0); \
        _Pragma("unroll")                                                        \
        for (int r = 0; r < 16; ++r)                                             \
            rmin0[r] = fminf(fminf(accX[r], accY[r]), rmin0[r]);                 \
        accX = __builtin_amdgcn_mfma_f32_32x32x16_bf16(afrag1, bx, z, 0, 0, 0);  \
        accY = __builtin_amdgcn_mfma_f32_32x32x16_bf16(afrag1, by, z, 0, 0, 0);  \
        _Pragma("unroll")                                                        \
        for (int r = 0; r < 16; ++r)                                             \
            rmin1[r] = fminf(fminf(accX[r], accY[r]), rmin1[r]);                 \
    }

// Reload one bf register with tile index tn (clamped to the last tile; the
// tail re-reads tile 63 harmlessly — min is idempotent).
#define CD_LOAD(bf, tn)                                                          \
    {                                                                            \
        int tt = (tn) < NTILE ? (tn) : NTILE - 1;                                \
        bf = *(const short8*)(gB + (size_t)tt * 512);                            \
    }

__global__ __launch_bounds__(THREADS, 2)    // 256-reg budget: pure arch VGPRs, no AGPR tax
void cd_mfma32(const unsigned short* __restrict__ A1, const unsigned short* __restrict__ B1,
               const unsigned short* __restrict__ A2, const unsigned short* __restrict__ B2,
               int* __restrict__ out) {
    int bid = blockIdx.x;
    const int c    = bid & (NCHUNK - 1);  bid >>= 2;
    const int rb   = bid & (ROWBLK - 1);  bid >>= 5;
    const int b    = bid & (B_ - 1);      bid >>= 2;
    const int pass = bid;                               // 0: dist1, 1: dist2

    const unsigned short* __restrict__ Ap = pass ? A2 : A1;
    const unsigned short* __restrict__ Bp = pass ? B1 : B2;
    int* __restrict__ o = out + (size_t)pass * B_ * NPT;

    const int lane = threadIdx.x & 63;
    const int w    = threadIdx.x >> 6;
    const int l31  = lane & 31;
    const int kg   = lane >> 5;            // k-half: k = kg*8 + idx

    const size_t bbase   = (size_t)b * NPT;
    const int    rowBase = rb * 256 + w * 64;

    // A fragments (linear layout), resident for the whole sweep
    short8 afrag0 = *(const short8*)(Ap + (bbase + rowBase +  0 + l31) * 16 + kg * 8);
    short8 afrag1 = *(const short8*)(Ap + (bbase + rowBase + 32 + l31) * 16 + kg * 8);

    f32x16 rmin0, rmin1;
    #pragma unroll
    for (int r = 0; r < 16; ++r) {
        rmin0[r] = __int_as_float(PINF_I);
        rmin1[r] = __int_as_float(PINF_I);
    }

    // B chunk base, split-K: 32-pt group = 512 ushorts; lane reads
    // kg*256 + l31*8 -> each wave instruction covers a contiguous 1 KB.
    const unsigned short* __restrict__ gB =
        Bp + (bbase + (size_t)c * CCOLS) * 16 + kg * 256 + l31 * 8;

    // Prime 8 tiles in flight (two 4-tile banks)
    short8 bf0, bf1, bf2, bf3, bf4, bf5, bf6, bf7;
    CD_LOAD(bf0, 0) CD_LOAD(bf1, 1) CD_LOAD(bf2, 2) CD_LOAD(bf3, 3)
    CD_LOAD(bf4, 4) CD_LOAD(bf5, 5) CD_LOAD(bf6, 6) CD_LOAD(bf7, 7)

    // Steady state: compute a 2-tile pair, then reload those regs for t+8.
    for (int t = 0; t < NTILE; t += 8) {
        CD_PAIR(bf0, bf1)
        CD_LOAD(bf0, t + 8)  CD_LOAD(bf1, t + 9)
        CD_PAIR(bf2, bf3)
        CD_LOAD(bf2, t + 10) CD_LOAD(bf3, t + 11)
        CD_PAIR(bf4, bf5)
        CD_LOAD(bf4, t + 12) CD_LOAD(bf5, t + 13)
        CD_PAIR(bf6, bf7)
        CD_LOAD(bf6, t + 14) CD_LOAD(bf7, t + 15)
    }

    // Epilogue: butterfly row-mins across 32 col-slots, one atomic per row
    #pragma unroll
    for (int rt = 0; rt < 2; ++rt) {
        #pragma unroll
        for (int r = 0; r < 16; ++r) {
            float v = rt ? rmin1[r] : rmin0[r];
            v = fminf(v, __shfl_xor(v, 1, 64));
            v = fminf(v, __shfl_xor(v, 2, 64));
            v = fminf(v, __shfl_xor(v, 4, 64));
            v = fminf(v, __shfl_xor(v, 8, 64));
            v = fminf(v, __shfl_xor(v, 16, 64));
            if (l31 == 0) {
                int row = rowBase + rt * 32 + (r & 3) + 8 * (r >> 2) + 4 * kg;
                atomicMin(&o[bbase + row], __float_as_int(fmaxf(v, 0.f)));
            }
        }
    }
}

extern "C" void kernel_launch(void* const* d_in, const int* in_sizes, int n_in,
                              void* d_out, int out_size, void* d_ws, size_t ws_size,
                              hipStream_t stream) {
    const float* xyz1 = (const float*)d_in[0];
    const float* xyz2 = (const float*)d_in[1];

    const size_t PSZ = (size_t)B_ * NPT * 16;       // ushorts per packed array
    unsigned short* A1 = (unsigned short*)d_ws;     // 4 x 1 MB in d_ws
    unsigned short* B1 = A1 + PSZ;
    unsigned short* A2 = B1 + PSZ;
    unsigned short* B2 = A2 + PSZ;

    cd_pack<<<(B_ * NPT + THREADS - 1) / THREADS, THREADS, 0, stream>>>(
        xyz1, xyz2, A1, B1, A2, B2, (int*)d_out);

    cd_mfma32<<<2 * B_ * ROWBLK * NCHUNK, THREADS, 0, stream>>>(
        A1, B1, A2, B2, (int*)d_out);
}

// Round 19
// 36.284 us; speedup vs baseline: 1.3077x; 1.0453x over previous
//
#include <hip/hip_runtime.h>

// ChamferDistance: B=4, N=M=8192, fp32 3-D points.
// R19: SCAFFOLDING-STRIP round. R5-R18: five binaries at 37.1-37.9 µs across
// every occupancy/prefetch/VALU/LDS/work variation — the in-loop instruction
// stream does not set the number. Never varied: 2 serialized launches + init
// pass + global atomicMin + d_ws round-trip. Graph-replay dur_us includes
// per-launch overhead (rocprof.md: ~10 µs can dominate) and R15 proved
// profiled durs are inflated, so true fast-kernel time was never observed.
// This round: ONE kernel, NO d_ws, NO atomics, NO init.
//   - NCHUNK=1: block owns its 256 rows completely -> direct store.
//   - A-form packed in-register (lane packs its own row, keeps its k-half).
//   - B-form packed in-kernel into 32 KB LDS stages (1024 pts x 8 stages,
//     proven split-K conflict-free layout), 2 barriers/stage.
//   - grid 256 = 1 block/CU (occupancy proven non-binding: R18==R12).
// Math verified since R4 (absmax 0.0156): d = n1+n2-2x.y, hi/lo bf16 K=16;
// A=[-2xh(3),-2xl(3),-2xh(3),n1h,n1l,1,1,0..], B=[yh(3),yh(3),yl(3),1,1,n2h,n2l,0..]
// C layout 32x32: col=lane&31, row=(r&3)+8*(r>>2)+4*(lane>>5).

typedef short  short8 __attribute__((ext_vector_type(8)));
typedef float  f32x16 __attribute__((ext_vector_type(16)));

#define B_       4
#define NPT      8192
#define THREADS  256
#define NROWBLK  32              // 256 rows per block
#define STAGEPTS 1024            // B points per LDS stage (32 KB packed)
#define NSTAGE   (NPT / STAGEPTS)    // 8
#define NTILE    (STAGEPTS / 32)     // 32 tiles per stage
#define PINF_I   0x7f800000

__device__ __forceinline__ unsigned short f2bf(float x) {
    unsigned u = __float_as_uint(x);
    u += 0x7fff + ((u >> 16) & 1);
    return (unsigned short)(u >> 16);
}
__device__ __forceinline__ float bf2f(unsigned short b) {
    return __uint_as_float(((unsigned)b) << 16);
}
#define PK2(a, b) ((((unsigned)(b)) << 16) | (unsigned)(a))

// Pack one row-point into the lane's A-fragment half (kg = lane>>5).
__device__ __forceinline__ short8 packA(const float* __restrict__ p, int kg) {
    const unsigned short one = 0x3f80;
    float x0 = p[0], x1 = p[1], x2 = p[2];
    unsigned short h0 = f2bf(x0), h1 = f2bf(x1), h2 = f2bf(x2);
    unsigned short l0 = f2bf(x0 - bf2f(h0)), l1 = f2bf(x1 - bf2f(h1)), l2 = f2bf(x2 - bf2f(h2));
    unsigned short m0 = f2bf(-2.f * bf2f(h0)), m1 = f2bf(-2.f * bf2f(h1)), m2 = f2bf(-2.f * bf2f(h2));
    unsigned short q0 = f2bf(-2.f * bf2f(l0)), q1 = f2bf(-2.f * bf2f(l1)), q2 = f2bf(-2.f * bf2f(l2));
    float n = x0*x0 + x1*x1 + x2*x2;
    unsigned short nh = f2bf(n), nl = f2bf(n - bf2f(nh));
    short8 r;
    if (kg == 0) {
        r[0] = (short)m0; r[1] = (short)m1; r[2] = (short)m2; r[3] = (short)q0;
        r[4] = (short)q1; r[5] = (short)q2; r[6] = (short)m0; r[7] = (short)m1;
    } else {
        r[0] = (short)m2; r[1] = (short)nh; r[2] = (short)nl; r[3] = (short)one;
        r[4] = (short)one; r[5] = 0; r[6] = 0; r[7] = 0;
    }
    return r;
}

// Pair-compute on two LDS B tiles: one 32-reg acc pair live at a time.
#define CD_PAIR(bx, by)                                                          \
    {                                                                            \
        f32x16 z = {0.f};                                                        \
        f32x16 accX = __builtin_amdgcn_mfma_f32_32x32x16_bf16(afrag0, bx, z, 0, 0, 0); \
        f32x16 accY = __builtin_amdgcn_mfma_f32_32x32x16_bf16(afrag0, by, z, 0, 0, 0); \
        _Pragma("unroll")                                                        \
        for (int r = 0; r < 16; ++r)                                             \
            rmin0[r] = fminf(fminf(accX[r], accY[r]), rmin0[r]);                 \
        accX = __builtin_amdgcn_mfma_f32_32x32x16_bf16(afrag1, bx, z, 0, 0, 0);  \
        accY = __builtin_amdgcn_mfma_f32_32x32x16_bf16(afrag1, by, z, 0, 0, 0);  \
        _Pragma("unroll")                                                        \
        for (int r = 0; r < 16; ++r)                                             \
            rmin1[r] = fminf(fminf(accX[r], accY[r]), rmin1[r]);                 \
    }

__global__ __launch_bounds__(THREADS, 4)
void cd_fused(const float* __restrict__ xyz1, const float* __restrict__ xyz2,
              float* __restrict__ out) {
    __shared__ uint4 ysh[STAGEPTS * 2];    // 32 KB: split-K packed B stage

    int bid = blockIdx.x;
    const int rb   = bid & (NROWBLK - 1);  bid >>= 5;
    const int b    = bid & (B_ - 1);       bid >>= 2;
    const int pass = bid;                   // 0: dist1 (rows=cloud1), 1: dist2

    const float* __restrict__ xa = pass ? xyz2 : xyz1;   // row cloud
    const float* __restrict__ xb = pass ? xyz1 : xyz2;   // col cloud
    float* __restrict__ o = out + (size_t)pass * B_ * NPT;

    const int tid  = threadIdx.x;
    const int lane = tid & 63;
    const int w    = tid >> 6;
    const int l31  = lane & 31;
    const int kg   = lane >> 5;

    const size_t bbase   = (size_t)b * NPT;
    const int    rowBase = rb * 256 + w * 64;
    const unsigned short one = 0x3f80;

    // In-register A fragments: lane packs its own two rows, keeps its k-half.
    short8 afrag0 = packA(xa + (bbase + rowBase + l31) * 3, kg);
    short8 afrag1 = packA(xa + (bbase + rowBase + 32 + l31) * 3, kg);

    f32x16 rmin0, rmin1;
    #pragma unroll
    for (int r = 0; r < 16; ++r) {
        rmin0[r] = __int_as_float(PINF_I);
        rmin1[r] = __int_as_float(PINF_I);
    }

    const unsigned short* bsh = (const unsigned short*)ysh;

    for (int s = 0; s < NSTAGE; ++s) {
        // Pack 1024 B points into LDS (4 per thread), split-K layout:
        // group g = p>>5: uint4 [g*64 + slot] = k0..7, [g*64+32+slot] = k8..15
        #pragma unroll
        for (int k = 0; k < 4; ++k) {
            const int p = k * 256 + tid;
            const float* yp = xb + (bbase + (size_t)s * STAGEPTS + p) * 3;
            float y0 = yp[0], y1 = yp[1], y2 = yp[2];
            unsigned short h0 = f2bf(y0), h1 = f2bf(y1), h2 = f2bf(y2);
            unsigned short l0 = f2bf(y0 - bf2f(h0));
            unsigned short l1 = f2bf(y1 - bf2f(h1));
            unsigned short l2 = f2bf(y2 - bf2f(h2));
            float n = y0*y0 + y1*y1 + y2*y2;
            unsigned short nh = f2bf(n), nl = f2bf(n - bf2f(nh));
            const int g = p >> 5, sl = p & 31;
            ysh[g * 64 + sl]      = make_uint4(PK2(h0, h1), PK2(h2, h0), PK2(h1, h2), PK2(l0, l1));
            ysh[g * 64 + 32 + sl] = make_uint4(PK2(l2, one), PK2(one, nh), PK2(nl, 0), PK2(0, 0));
        }
        __syncthreads();

        // 16 tile-pairs of pure LDS compute (conflict-free contiguous reads)
        #pragma unroll 4
        for (int pr = 0; pr < NTILE / 2; ++pr) {
            short8 bf0 = *(const short8*)(bsh + (pr * 2)     * 512 + kg * 256 + l31 * 8);
            short8 bf1 = *(const short8*)(bsh + (pr * 2 + 1) * 512 + kg * 256 + l31 * 8);
            CD_PAIR(bf0, bf1)
        }
        __syncthreads();
    }

    // Epilogue: butterfly across 32 col-slots; DIRECT store (block owns rows).
    #pragma unroll
    for (int rt = 0; rt < 2; ++rt) {
        #pragma unroll
        for (int r = 0; r < 16; ++r) {
            float v = rt ? rmin1[r] : rmin0[r];
            v = fminf(v, __shfl_xor(v, 1, 64));
            v = fminf(v, __shfl_xor(v, 2, 64));
            v = fminf(v, __shfl_xor(v, 4, 64));
            v = fminf(v, __shfl_xor(v, 8, 64));
            v = fminf(v, __shfl_xor(v, 16, 64));
            if (l31 == 0) {
                int row = rowBase + rt * 32 + (r & 3) + 8 * (r >> 2) + 4 * kg;
                o[bbase + row] = fmaxf(v, 0.f);
            }
        }
    }
}

extern "C" void kernel_launch(void* const* d_in, const int* in_sizes, int n_in,
                              void* d_out, int out_size, void* d_ws, size_t ws_size,
                              hipStream_t stream) {
    const float* xyz1 = (const float*)d_in[0];
    const float* xyz2 = (const float*)d_in[1];
    // ONE launch, no workspace, no init, no atomics.
    cd_fused<<<2 * B_ * NROWBLK, THREADS, 0, stream>>>(xyz1, xyz2, (float*)d_out);
}

// Round 20
// 30.233 us; speedup vs baseline: 1.5694x; 1.2001x over previous
//
#include <hip/hip_runtime.h>

// ChamferDistance: B=4, N=M=8192, fp32 3-D points.
// R20: R19's LDS-resident single-kernel + 4 waves/SIMD via in-block column
// split. R19 counters (first clean, timed==profiled): FETCH 3MB, conflicts 0,
// MfmaUtil 15%, VALUBusy 24%, Occupancy 9.9% = 1 wave/SIMD — issue-sum 7.6 µs
// vs 39.6 wall = pure latency exposure, no TLP. Root geometry: 64 rows/wave x
// 65536 rows = exactly 1024 waves = 1 per SIMD. Fix: 512-thread blocks,
// 8 waves; wave w owns row-tile (w&3) and column-HALF (w>>2) of each stage
// (16 of 32 tiles); halves merge block-locally via LDS, h=0 waves store.
// Grid 512 = 2 blocks/CU = 4 waves/SIMD. Single afrag/wave -> ~80 regs under
// the 128 cap at launch_bounds(512,4). LDS 32KB/block -> 64KB/CU.
// Math verified since R4 (absmax 0.0156): d = n1+n2-2x.y, hi/lo bf16 K=16;
// C layout 32x32: col=lane&31, row=(r&3)+8*(r>>2)+4*(lane>>5).

typedef short  short8 __attribute__((ext_vector_type(8)));
typedef float  f32x16 __attribute__((ext_vector_type(16)));

#define B_       4
#define NPT      8192
#define THREADS  512
#define NROWBLK  64              // 128 rows per block
#define STAGEPTS 1024            // B points per LDS stage (32 KB packed)
#define NSTAGE   (NPT / STAGEPTS)    // 8
#define PINF_I   0x7f800000

__device__ __forceinline__ unsigned short f2bf(float x) {
    unsigned u = __float_as_uint(x);
    u += 0x7fff + ((u >> 16) & 1);
    return (unsigned short)(u >> 16);
}
__device__ __forceinline__ float bf2f(unsigned short b) {
    return __uint_as_float(((unsigned)b) << 16);
}
#define PK2(a, b) ((((unsigned)(b)) << 16) | (unsigned)(a))

// Pack one row-point into the lane's A-fragment half (kg = lane>>5).
__device__ __forceinline__ short8 packA(const float* __restrict__ p, int kg) {
    const unsigned short one = 0x3f80;
    float x0 = p[0], x1 = p[1], x2 = p[2];
    unsigned short h0 = f2bf(x0), h1 = f2bf(x1), h2 = f2bf(x2);
    unsigned short l0 = f2bf(x0 - bf2f(h0)), l1 = f2bf(x1 - bf2f(h1)), l2 = f2bf(x2 - bf2f(h2));
    unsigned short m0 = f2bf(-2.f * bf2f(h0)), m1 = f2bf(-2.f * bf2f(h1)), m2 = f2bf(-2.f * bf2f(h2));
    unsigned short q0 = f2bf(-2.f * bf2f(l0)), q1 = f2bf(-2.f * bf2f(l1)), q2 = f2bf(-2.f * bf2f(l2));
    float n = x0*x0 + x1*x1 + x2*x2;
    unsigned short nh = f2bf(n), nl = f2bf(n - bf2f(nh));
    short8 r;
    if (kg == 0) {
        r[0] = (short)m0; r[1] = (short)m1; r[2] = (short)m2; r[3] = (short)q0;
        r[4] = (short)q1; r[5] = (short)q2; r[6] = (short)m0; r[7] = (short)m1;
    } else {
        r[0] = (short)m2; r[1] = (short)nh; r[2] = (short)nl; r[3] = (short)one;
        r[4] = (short)one; r[5] = 0; r[6] = 0; r[7] = 0;
    }
    return r;
}

__global__ __launch_bounds__(THREADS, 4)   // 4 waves/EU -> 2 blocks/CU, 128-reg cap
void cd_fused(const float* __restrict__ xyz1, const float* __restrict__ xyz2,
              float* __restrict__ out) {
    __shared__ uint4 ysh[STAGEPTS * 2];    // 32 KB: split-K packed B stage

    int bid = blockIdx.x;
    const int rb   = bid & (NROWBLK - 1);  bid >>= 6;
    const int b    = bid & (B_ - 1);       bid >>= 2;
    const int pass = bid;                   // 0: dist1 (rows=cloud1), 1: dist2

    const float* __restrict__ xa = pass ? xyz2 : xyz1;   // row cloud
    const float* __restrict__ xb = pass ? xyz1 : xyz2;   // col cloud
    float* __restrict__ o = out + (size_t)pass * B_ * NPT;

    const int tid  = threadIdx.x;
    const int lane = tid & 63;
    const int w    = tid >> 6;             // 0..7
    const int rt   = w & 3;                // row-tile within block
    const int h    = w >> 2;               // column half (0 or 1)
    const int l31  = lane & 31;
    const int kg   = lane >> 5;
    const unsigned short one = 0x3f80;

    const size_t bbase = (size_t)b * NPT;
    const int    myRow = rb * 128 + rt * 32;

    // In-register A fragment: lane packs its own row, keeps its k-half.
    short8 afrag = packA(xa + (bbase + myRow + l31) * 3, kg);

    f32x16 rmin;
    #pragma unroll
    for (int r = 0; r < 16; ++r) rmin[r] = __int_as_float(PINF_I);

    const unsigned short* bsh = (const unsigned short*)ysh;

    for (int s = 0; s < NSTAGE; ++s) {
        // Pack 1024 B points into LDS (2 per thread), split-K layout:
        // group g = p>>5: uint4 [g*64 + slot] = k0..7, [g*64+32+slot] = k8..15
        #pragma unroll
        for (int k = 0; k < 2; ++k) {
            const int p = k * THREADS + tid;
            const float* yp = xb + (bbase + (size_t)s * STAGEPTS + p) * 3;
            float y0 = yp[0], y1 = yp[1], y2 = yp[2];
            unsigned short h0 = f2bf(y0), h1 = f2bf(y1), h2 = f2bf(y2);
            unsigned short l0 = f2bf(y0 - bf2f(h0));
            unsigned short l1 = f2bf(y1 - bf2f(h1));
            unsigned short l2 = f2bf(y2 - bf2f(h2));
            float n = y0*y0 + y1*y1 + y2*y2;
            unsigned short nh = f2bf(n), nl = f2bf(n - bf2f(nh));
            const int g = p >> 5, sl = p & 31;
            ysh[g * 64 + sl]      = make_uint4(PK2(h0, h1), PK2(h2, h0), PK2(h1, h2), PK2(l0, l1));
            ysh[g * 64 + 32 + sl] = make_uint4(PK2(l2, one), PK2(one, nh), PK2(nl, 0), PK2(0, 0));
        }
        __syncthreads();

        // This wave's column half: 16 tiles = 8 pairs of pure LDS compute.
        #pragma unroll
        for (int pr = 0; pr < 8; ++pr) {
            const int t0 = h * 16 + pr * 2;
            short8 bf0 = *(const short8*)(bsh + (size_t)t0 * 512 + kg * 256 + l31 * 8);
            short8 bf1 = *(const short8*)(bsh + (size_t)(t0 + 1) * 512 + kg * 256 + l31 * 8);
            f32x16 z = {0.f};
            f32x16 accX = __builtin_amdgcn_mfma_f32_32x32x16_bf16(afrag, bf0, z, 0, 0, 0);
            f32x16 accY = __builtin_amdgcn_mfma_f32_32x32x16_bf16(afrag, bf1, z, 0, 0, 0);
            #pragma unroll
            for (int r = 0; r < 16; ++r)
                rmin[r] = fminf(fminf(accX[r], accY[r]), rmin[r]);   // v_min3_f32
        }
        __syncthreads();
    }

    // Cross-half combine via LDS (reuse ysh; [rt][r][lane] = conflict-free).
    float* csh = (float*)ysh;              // 4 * 16 * 64 floats = 16 KB
    if (h == 1) {
        #pragma unroll
        for (int r = 0; r < 16; ++r)
            csh[rt * 1024 + r * 64 + lane] = rmin[r];
    }
    __syncthreads();
    if (h == 0) {
        #pragma unroll
        for (int r = 0; r < 16; ++r) {
            float v = fminf(rmin[r], csh[rt * 1024 + r * 64 + lane]);
            v = fminf(v, __shfl_xor(v, 1, 64));
            v = fminf(v, __shfl_xor(v, 2, 64));
            v = fminf(v, __shfl_xor(v, 4, 64));
            v = fminf(v, __shfl_xor(v, 8, 64));
            v = fminf(v, __shfl_xor(v, 16, 64));
            if (l31 == 0) {
                int row = myRow + (r & 3) + 8 * (r >> 2) + 4 * kg;
                o[bbase + row] = fmaxf(v, 0.f);
            }
        }
    }
}

extern "C" void kernel_launch(void* const* d_in, const int* in_sizes, int n_in,
                              void* d_out, int out_size, void* d_ws, size_t ws_size,
                              hipStream_t stream) {
    const float* xyz1 = (const float*)d_in[0];
    const float* xyz2 = (const float*)d_in[1];
    // ONE launch, no workspace, no init, no atomics.
    cd_fused<<<2 * B_ * NROWBLK, THREADS, 0, stream>>>(xyz1, xyz2, (float*)d_out);
}